// Round 1
// baseline (81.316 us; speedup 1.0000x reference)
//
#include <hip/hip_runtime.h>

#define NN     4096
#define TT     3
#define DD     20
#define EE     131072
#define ADIM   128
#define NHEADS 2
#define NEG    0.2f
#define WPR    (NN / 8)   // 512 uint32 mask words per row (4 bits per ordered pair)

// ---------------- kernel 1: scatter edges into 4-bit-per-pair type bitmask ----
__global__ void k_scatter(const int* __restrict__ el, unsigned int* __restrict__ mask) {
    int idx = blockIdx.x * blockDim.x + threadIdx.x;
    if (idx >= TT * EE) return;
    int t = idx / EE;
    int e = idx - t * EE;
    unsigned int src = (unsigned int)el[t * 2 * EE + e];
    unsigned int tgt = (unsigned int)el[t * 2 * EE + EE + e];
    unsigned int p1 = src * NN + tgt;
    unsigned int p2 = tgt * NN + src;
    // nibble layout: pair p lives in word p>>3, nibble p&7; bit t within nibble.
    atomicOr(&mask[p1 >> 3], 1u << (((p1 & 7u) << 2) + (unsigned)t));
    atomicOr(&mask[p2 >> 3], 1u << (((p2 & 7u) << 2) + (unsigned)t));
}

// ---------------- kernel 2: s0 = inputs @ lin_w.T + lin_b ---------------------
__global__ void k_init_scores(const float* __restrict__ inputs,
                              const float* __restrict__ lin_w,
                              const float* __restrict__ lin_b,
                              float* __restrict__ s) {
    int row  = blockIdx.x;
    int lane = threadIdx.x;                       // 64 threads = 1 wave
    const float* rp = inputs + row * ADIM;
    float v = rp[lane] * lin_w[lane] + rp[lane + 64] * lin_w[lane + 64];
    #pragma unroll
    for (int off = 32; off > 0; off >>= 1) v += __shfl_down(v, off);
    if (lane == 0) s[row] = v + lin_b[0];
}

// ---------------- kernel 3: S = sum(s) ---------------------------------------
__global__ void k_sum(const float* __restrict__ s, float* __restrict__ out) {
    __shared__ float red[16];
    int tid = threadIdx.x;                        // 1024 threads
    float v = s[tid] + s[tid + 1024] + s[tid + 2048] + s[tid + 3072];
    #pragma unroll
    for (int off = 32; off > 0; off >>= 1) v += __shfl_down(v, off);
    if ((tid & 63) == 0) red[tid >> 6] = v;
    __syncthreads();
    if (tid < 64) {
        float v2 = (tid < 16) ? red[tid] : 0.f;
        #pragma unroll
        for (int off = 8; off > 0; off >>= 1) v2 += __shfl_down(v2, off);
        if (tid == 0) out[0] = v2;
    }
}

// ---------------- kernel 4: one GNN layer (both heads fused), row per block ---
__global__ __launch_bounds__(256) void k_layer(const unsigned int* __restrict__ mask,
                                               const float* __restrict__ s_in,
                                               const float* __restrict__ Ssum,
                                               const float* __restrict__ att_w,
                                               const float* __restrict__ edge_emb,
                                               float* __restrict__ s_out,
                                               int layer) {
    __shared__ float et[NHEADS][TT];
    __shared__ float lut[NHEADS][8];
    __shared__ float w0s[NHEADS], wNs[NHEADS];
    int tid = threadIdx.x;

    if (tid < NHEADS * TT) {
        int h = tid / TT, t = tid % TT;
        const float* w = att_w + (layer * NHEADS + h) * (DD + 2);
        float acc = 0.f;
        #pragma unroll
        for (int d = 0; d < DD; d++) acc += edge_emb[t * DD + d] * w[1 + d];
        et[h][t] = acc;
        if (t == 0) { w0s[h] = w[0]; wNs[h] = w[DD + 1]; }
    }
    __syncthreads();
    if (tid < NHEADS * 8) {
        int h = tid >> 3, m = tid & 7;
        lut[h][m] = (m & 1 ? et[h][0] : 0.f) + (m & 2 ? et[h][1] : 0.f) + (m & 4 ? et[h][2] : 0.f);
    }
    __syncthreads();

    int row = blockIdx.x;
    float si = s_in[row];
    const unsigned int* mrow = mask + (size_t)row * WPR;
    float a0 = w0s[0] * si, a1 = w0s[1] * si;
    float b0 = wNs[0],      b1 = wNs[1];

    float num0 = 0.f, den0 = 0.f, num1 = 0.f, den1 = 0.f;
    for (int w = tid; w < WPR; w += 256) {
        unsigned int m = mrow[w];
        if (m == 0u) continue;
        int jbase = w << 3;
        #pragma unroll
        for (int k = 0; k < 8; k++) {
            unsigned int nib = (m >> (k * 4)) & 0xFu;
            if (!nib) continue;
            float c  = (float)__popc(nib);
            float sj = s_in[jbase + k];
            // head 0
            float l0 = c * (a0 + b0 * sj) + lut[0][nib];
            l0 = (l0 > 0.f) ? l0 : NEG * l0;
            float e0 = __expf(l0) - 1.0f;
            num0 += e0 * sj; den0 += e0;
            // head 1
            float l1 = c * (a1 + b1 * sj) + lut[1][nib];
            l1 = (l1 > 0.f) ? l1 : NEG * l1;
            float e1 = __expf(l1) - 1.0f;
            num1 += e1 * sj; den1 += e1;
        }
    }

    // block reduction of 4 accumulators
    #pragma unroll
    for (int off = 32; off > 0; off >>= 1) {
        num0 += __shfl_down(num0, off); den0 += __shfl_down(den0, off);
        num1 += __shfl_down(num1, off); den1 += __shfl_down(den1, off);
    }
    __shared__ float red[4][4];
    int wid = tid >> 6, lane = tid & 63;
    if (lane == 0) { red[wid][0] = num0; red[wid][1] = den0; red[wid][2] = num1; red[wid][3] = den1; }
    __syncthreads();
    if (tid == 0) {
        float n0 = red[0][0] + red[1][0] + red[2][0] + red[3][0];
        float d0 = red[0][1] + red[1][1] + red[2][1] + red[3][1];
        float n1 = red[0][2] + red[1][2] + red[2][2] + red[3][2];
        float d1 = red[0][3] + red[1][3] + red[2][3] + red[3][3];
        float S  = Ssum[0];
        float o0 = (S + n0) / ((float)NN + d0);
        float o1 = (S + n1) / ((float)NN + d1);
        s_out[row] = 0.5f * (o0 + o1);
    }
}

// ---------------- host-side launcher -----------------------------------------
extern "C" void kernel_launch(void* const* d_in, const int* in_sizes, int n_in,
                              void* d_out, int out_size, void* d_ws, size_t ws_size,
                              hipStream_t stream) {
    const float* inputs   = (const float*)d_in[0];
    const float* lin_w    = (const float*)d_in[1];
    const float* lin_b    = (const float*)d_in[2];
    const float* edge_emb = (const float*)d_in[3];
    const float* att_w    = (const float*)d_in[4];
    const int*   el       = (const int*)d_in[5];
    float* out = (float*)d_out;

    char* ws = (char*)d_ws;
    unsigned int* mask = (unsigned int*)ws;                       // 8 MB
    float* s0   = (float*)(ws + 8u * 1024u * 1024u);              // 16 KB
    float* s1   = (float*)(ws + 8u * 1024u * 1024u + 16384u);     // 16 KB
    float* ssum = (float*)(ws + 8u * 1024u * 1024u + 32768u);     // 4 B

    hipMemsetAsync(mask, 0, (size_t)NN * NN / 2, stream);
    k_scatter<<<(TT * EE + 255) / 256, 256, 0, stream>>>(el, mask);
    k_init_scores<<<NN, 64, 0, stream>>>(inputs, lin_w, lin_b, s0);

    k_sum<<<1, 1024, 0, stream>>>(s0, ssum);
    k_layer<<<NN, 256, 0, stream>>>(mask, s0, ssum, att_w, edge_emb, s1, 0);

    k_sum<<<1, 1024, 0, stream>>>(s1, ssum);
    k_layer<<<NN, 256, 0, stream>>>(mask, s1, ssum, att_w, edge_emb, out, 1);
}